// Round 4
// baseline (1248.587 us; speedup 1.0000x reference)
//
#include <hip/hip_runtime.h>
#include <hip/hip_bf16.h>

#define B_ 16
#define S_ 80
#define D_ 512
#define H_ 64
#define DI_ 2048
#define L_ 6
#define G4H 256            // 4*H
#define NROW (B_ * S_)     // 1280 rows = (b, s)
#define EPS_ 1e-6f

typedef __attribute__((ext_vector_type(8))) short short8;
typedef __attribute__((ext_vector_type(4))) float f32x4;

// ---------------- math helpers ----------------
__device__ __forceinline__ float sigmoidf_(float x) {
    return __fdividef(1.0f, 1.0f + __expf(-x));
}
__device__ __forceinline__ float tanh_(float x) {
    return __fdividef(2.0f, 1.0f + __expf(-2.0f * x)) - 1.0f;
}
__device__ __forceinline__ short f2bf(float f) {
    __hip_bfloat16 h = __float2bfloat16(f);   // RNE
    return *reinterpret_cast<short*>(&h);
}

// ---------------- LayerNorm: one block per row, D=512, 256 threads; bf16 out ----------------
__global__ __launch_bounds__(256)
void ln_kernel(const float* __restrict__ x, const float* __restrict__ g,
               const float* __restrict__ b, __hip_bfloat16* __restrict__ out) {
    int row = blockIdx.x;
    int t = threadIdx.x;
    const float* xr = x + (size_t)row * D_;
    float v0 = xr[t], v1 = xr[t + 256];
    __shared__ float red[256];
    red[t] = v0 + v1;
    __syncthreads();
    for (int o = 128; o > 0; o >>= 1) { if (t < o) red[t] += red[t + o]; __syncthreads(); }
    float m = red[0] * (1.0f / (float)D_);
    __syncthreads();
    float d0 = v0 - m, d1 = v1 - m;
    red[t] = d0 * d0 + d1 * d1;
    __syncthreads();
    for (int o = 128; o > 0; o >>= 1) { if (t < o) red[t] += red[t + o]; __syncthreads(); }
    float rs = rsqrtf(red[0] * (1.0f / (float)D_) + EPS_);
    __hip_bfloat16* orow = out + (size_t)row * D_;
    orow[t]       = __float2bfloat16(d0 * rs * g[t]       + b[t]);
    orow[t + 256] = __float2bfloat16(d1 * rs * g[t + 256] + b[t + 256]);
}

// ---------------- bf16 MFMA GEMM: C[M,N] = A[M,K] @ W[N,K]^T (+bias)(+relu)(+res) -----------
// OUT_MODE: 0 = fp32 row-major, 1 = bf16 row-major, 2 = fp32 xg2 layout [s][gate][hw][b]
template<int WITH_BIAS, int WITH_RELU, int WITH_RES, int OUT_MODE>
__global__ __launch_bounds__(256)
void mfma_gemm(const __hip_bfloat16* __restrict__ A, const float* __restrict__ W,
               const float* __restrict__ bias, const float* __restrict__ res,
               void* __restrict__ C, int M, int N, int K) {
    const int LDT = 40;  // LDS row stride in bf16 elems
    __shared__ short As[64 * LDT];
    __shared__ short Ws[64 * LDT];

    int tid  = threadIdx.x;
    int wave = tid >> 6, lane = tid & 63;
    int quad = lane >> 4, l16 = lane & 15;
    int m_off = (wave >> 1) * 32, n_off = (wave & 1) * 32;
    int m0 = blockIdx.y * 64, n0 = blockIdx.x * 64;

    int r = tid >> 2, c = tid & 3;           // staging: row 0..63, 8-elem chunk 0..3
    const short* Ag = reinterpret_cast<const short*>(A);

    f32x4 acc00 = {0.f,0.f,0.f,0.f}, acc01 = acc00, acc10 = acc00, acc11 = acc00;

    for (int k0 = 0; k0 < K; k0 += 32) {
        short8 av = *reinterpret_cast<const short8*>(&Ag[(size_t)(m0 + r) * K + k0 + c * 8]);
        const float* wrow = &W[(size_t)(n0 + r) * K + k0 + c * 8];
        float4 w0 = *reinterpret_cast<const float4*>(wrow);
        float4 w1 = *reinterpret_cast<const float4*>(wrow + 4);
        short8 wv;
        wv[0] = f2bf(w0.x); wv[1] = f2bf(w0.y); wv[2] = f2bf(w0.z); wv[3] = f2bf(w0.w);
        wv[4] = f2bf(w1.x); wv[5] = f2bf(w1.y); wv[6] = f2bf(w1.z); wv[7] = f2bf(w1.w);

        __syncthreads();
        *reinterpret_cast<short8*>(&As[r * LDT + c * 8]) = av;
        *reinterpret_cast<short8*>(&Ws[r * LDT + c * 8]) = wv;
        __syncthreads();

        short8 a0 = *reinterpret_cast<const short8*>(&As[(m_off + l16) * LDT + quad * 8]);
        short8 a1 = *reinterpret_cast<const short8*>(&As[(m_off + 16 + l16) * LDT + quad * 8]);
        short8 b0 = *reinterpret_cast<const short8*>(&Ws[(n_off + l16) * LDT + quad * 8]);
        short8 b1 = *reinterpret_cast<const short8*>(&Ws[(n_off + 16 + l16) * LDT + quad * 8]);

        acc00 = __builtin_amdgcn_mfma_f32_16x16x32_bf16(a0, b0, acc00, 0, 0, 0);
        acc01 = __builtin_amdgcn_mfma_f32_16x16x32_bf16(a0, b1, acc01, 0, 0, 0);
        acc10 = __builtin_amdgcn_mfma_f32_16x16x32_bf16(a1, b0, acc10, 0, 0, 0);
        acc11 = __builtin_amdgcn_mfma_f32_16x16x32_bf16(a1, b1, acc11, 0, 0, 0);
    }

    f32x4 accs[2][2] = {{acc00, acc01}, {acc10, acc11}};
    #pragma unroll
    for (int fi = 0; fi < 2; fi++) {
        #pragma unroll
        for (int fj = 0; fj < 2; fj++) {
            int coln = n0 + n_off + fj * 16 + l16;
            float bv = WITH_BIAS ? bias[coln] : 0.0f;
            #pragma unroll
            for (int rr = 0; rr < 4; rr++) {
                int rowm = m0 + m_off + fi * 16 + quad * 4 + rr;
                float v = accs[fi][fj][rr];
                if (WITH_BIAS) v += bv;
                if (WITH_RELU) v = fmaxf(v, 0.0f);
                if (WITH_RES)  v += res[(size_t)rowm * N + coln];
                if (OUT_MODE == 0) {
                    reinterpret_cast<float*>(C)[(size_t)rowm * N + coln] = v;
                } else if (OUT_MODE == 1) {
                    reinterpret_cast<__hip_bfloat16*>(C)[(size_t)rowm * N + coln] = __float2bfloat16(v);
                } else {
                    // xg2[s][gate][hw][b]: rows are m = b*S + s, cols n = gate*64 + hw
                    int b_ = rowm / S_;
                    int s_ = rowm - b_ * S_;
                    int gate = coln >> 6, hw = coln & 63;
                    reinterpret_cast<float*>(C)[(((size_t)(s_ * 4 + gate) * 64 + hw) << 4) + b_] = v;
                }
            }
        }
    }
}

// ---------------- MFMA LSTM, 2 positions interleaved per block ----------------
// Grid (40, 2): block = (position pair {p, p+40}, batch half). 4 waves, M=8 (batch
// rows bh*8..bh*8+7 in C rows 0..7; rows 8..15 are zero/garbage, discarded).
// Each wave owns 16 hidden units (hw = wave*16 + l16) x 4 gates (gate-permuted cols).
// Per iteration both positions step once: 1 barrier, double-buffered h LDS (parity t&1).
// posA nonlinearity on quads 0-1; posB gates shuffled (lane^32) to quads 2-3 so every
// lane handles 4 states -> transcendental issue per step halved.
__global__ __launch_bounds__(256)
void lstm_mfma2_kernel(const float* __restrict__ xg2,  // [S][4][64][16] fp32
                       const float* __restrict__ whh,  // [4H, H] fp32
                       __hip_bfloat16* __restrict__ hlast) {  // [B, S, H]
    const int pair = blockIdx.x;        // 0..39
    const int bh   = blockIdx.y;        // 0..1
    const int iA = pair, iB = pair + 40;
    const int tid  = threadIdx.x;
    const int wave = tid >> 6, lane = tid & 63;
    const int quad = lane >> 4, l16 = lane & 15;
    const int hw   = wave * 16 + l16;
    const bool qlo = (quad < 2);        // quads 0-1: posA states; quads 2-3: posB states
    const int rrow = (quad & 1) * 4;    // batch-row base within the half (0 or 4)

    // B-fragments (whh -> bf16), constant across steps.
    short8 bfrag[4][2];
    #pragma unroll
    for (int gate = 0; gate < 4; gate++) {
        const float* wr = &whh[(size_t)(gate * 64 + hw) * H_];
        #pragma unroll
        for (int kc = 0; kc < 2; kc++) {
            float4 x0 = *(const float4*)(wr + kc * 32 + quad * 8);
            float4 x1 = *(const float4*)(wr + kc * 32 + quad * 8 + 4);
            short8 v;
            v[0] = f2bf(x0.x); v[1] = f2bf(x0.y); v[2] = f2bf(x0.z); v[3] = f2bf(x0.w);
            v[4] = f2bf(x1.x); v[5] = f2bf(x1.y); v[6] = f2bf(x1.z); v[7] = f2bf(x1.w);
            bfrag[gate][kc] = v;
        }
    }

    // h tiles: [pos][parity][row][col], 144B row stride; rows 8..15 stay zero.
    __shared__ __attribute__((aligned(16))) short hsh[2][2][16][72];
    for (int idx = tid; idx < 2 * 2 * 16 * 72; idx += 256)
        reinterpret_cast<short*>(hsh)[idx] = 0;

    float cst[4] = {0.f, 0.f, 0.f, 0.f};
    float hv[4]  = {0.f, 0.f, 0.f, 0.f};
    f32x4 xgvA[4], xgvB[4];
    const f32x4 zero4 = {0.f, 0.f, 0.f, 0.f};

    const int boff = bh * 8 + (quad & 1) * 4 + ((quad >> 1) ? 0 : 0); // base uses quad&1? no:
    // xg loads happen on quads 0-1 only; their batch quad index is `quad` (0 or 1):
    // batch group = bh*8 + quad*4 .. +3   (16B-aligned float4)
    // initial loads for t = 0
    {
        int sA = (0 == iA) ? (S_ - 1) : 0;
        int sB = (0 == iB) ? (S_ - 1) : 0;
        if (qlo) {
            #pragma unroll
            for (int g = 0; g < 4; g++) {
                xgvA[g] = *reinterpret_cast<const f32x4*>(
                    &xg2[(((size_t)(sA * 4 + g) * 64 + hw) << 4) + bh * 8 + quad * 4]);
                xgvB[g] = *reinterpret_cast<const f32x4*>(
                    &xg2[(((size_t)(sB * 4 + g) * 64 + hw) << 4) + bh * 8 + quad * 4]);
            }
        }
    }
    (void)boff;

    for (int t = 0; t < S_; t++) {
        const int pb = t & 1;
        if (t) {
            // publish h_{t-1}: quads 0-1 -> posA tile, quads 2-3 -> posB tile
            #pragma unroll
            for (int r = 0; r < 4; r++)
                hsh[qlo ? 0 : 1][pb][rrow + r][hw] = f2bf(hv[r]);
        }
        __syncthreads();

        short8 aA0 = *reinterpret_cast<const short8*>(&hsh[0][pb][l16][quad * 8]);
        short8 aA1 = *reinterpret_cast<const short8*>(&hsh[0][pb][l16][32 + quad * 8]);
        short8 aB0 = *reinterpret_cast<const short8*>(&hsh[1][pb][l16][quad * 8]);
        short8 aB1 = *reinterpret_cast<const short8*>(&hsh[1][pb][l16][32 + quad * 8]);

        f32x4 accA[4], accB[4];
        #pragma unroll
        for (int g = 0; g < 4; g++) {
            accA[g] = qlo ? xgvA[g] : zero4;
            accB[g] = qlo ? xgvB[g] : zero4;
        }
        #pragma unroll
        for (int g = 0; g < 4; g++) {
            accA[g] = __builtin_amdgcn_mfma_f32_16x16x32_bf16(aA0, bfrag[g][0], accA[g], 0, 0, 0);
            accA[g] = __builtin_amdgcn_mfma_f32_16x16x32_bf16(aA1, bfrag[g][1], accA[g], 0, 0, 0);
            accB[g] = __builtin_amdgcn_mfma_f32_16x16x32_bf16(aB0, bfrag[g][0], accB[g], 0, 0, 0);
            accB[g] = __builtin_amdgcn_mfma_f32_16x16x32_bf16(aB1, bfrag[g][1], accB[g], 0, 0, 0);
        }

        // prefetch xg for t+1 (drains at next iteration's barrier, ~500 cyc away)
        {
            int tn = (t + 1 < S_) ? (t + 1) : 0;
            int sA = (tn == iA) ? (S_ - 1) : ((tn == S_ - 1) ? iA : tn);
            int sB = (tn == iB) ? (S_ - 1) : ((tn == S_ - 1) ? iB : tn);
            if (qlo) {
                #pragma unroll
                for (int g = 0; g < 4; g++) {
                    xgvA[g] = *reinterpret_cast<const f32x4*>(
                        &xg2[(((size_t)(sA * 4 + g) * 64 + hw) << 4) + bh * 8 + quad * 4]);
                    xgvB[g] = *reinterpret_cast<const f32x4*>(
                        &xg2[(((size_t)(sB * 4 + g) * 64 + hw) << 4) + bh * 8 + quad * 4]);
                }
            }
        }

        // move posB gates to quads 2-3; every lane then owns 4 states of its position
        float gv[4][4];
        #pragma unroll
        for (int g = 0; g < 4; g++)
            #pragma unroll
            for (int r = 0; r < 4; r++) {
                float sh = __shfl(accB[g][r], lane ^ 32);
                gv[g][r] = qlo ? accA[g][r] : sh;
            }

        #pragma unroll
        for (int r = 0; r < 4; r++) {
            float ig = sigmoidf_(gv[0][r]);
            float fg = sigmoidf_(gv[1][r]);
            float gg = tanh_(gv[2][r]);
            float og = sigmoidf_(gv[3][r]);
            cst[r] = fg * cst[r] + ig * gg;
            hv[r]  = og * tanh_(cst[r]);
        }
    }

    // epilogue: lane's states belong to position (qlo ? iA : iB), batches bh*8+rrow+r
    const int myi = qlo ? iA : iB;
    #pragma unroll
    for (int r = 0; r < 4; r++) {
        int b = bh * 8 + rrow + r;
        hlast[((size_t)b * S_ + myi) * H_ + hw] = __float2bfloat16(hv[r]);
    }
}

// ---------------- final LN + projection to one logit per row ----------------
__global__ __launch_bounds__(256)
void final_kernel(const float* __restrict__ x, const float* __restrict__ g,
                  const float* __restrict__ b, const float* __restrict__ wprj,
                  float* __restrict__ out) {
    int row = blockIdx.x;
    int t = threadIdx.x;
    const float* xr = x + (size_t)row * D_;
    float v0 = xr[t], v1 = xr[t + 256];
    __shared__ float red[256];
    red[t] = v0 + v1;
    __syncthreads();
    for (int o = 128; o > 0; o >>= 1) { if (t < o) red[t] += red[t + o]; __syncthreads(); }
    float m = red[0] * (1.0f / (float)D_);
    __syncthreads();
    float d0 = v0 - m, d1 = v1 - m;
    red[t] = d0 * d0 + d1 * d1;
    __syncthreads();
    for (int o = 128; o > 0; o >>= 1) { if (t < o) red[t] += red[t + o]; __syncthreads(); }
    float rs = rsqrtf(red[0] * (1.0f / (float)D_) + EPS_);
    __syncthreads();
    float y0 = (d0 * rs * g[t] + b[t]) * wprj[t];
    float y1 = (d1 * rs * g[t + 256] + b[t + 256]) * wprj[t + 256];
    red[t] = y0 + y1;
    __syncthreads();
    for (int o = 128; o > 0; o >>= 1) { if (t < o) red[t] += red[t + o]; __syncthreads(); }
    if (t == 0) out[row] = red[0];
}

// ---------------- host ----------------
extern "C" void kernel_launch(void* const* d_in, const int* in_sizes, int n_in,
                              void* d_out, int out_size, void* d_ws, size_t ws_size,
                              hipStream_t stream) {
    const float* src   = (const float*)d_in[0];
    const float* ln1_g = (const float*)d_in[2];
    const float* ln1_b = (const float*)d_in[3];
    const float* wih   = (const float*)d_in[4];   // [L, 4H, D]
    const float* whh   = (const float*)d_in[5];   // [L, 4H, H]
    const float* wfc   = (const float*)d_in[6];   // [L, D, H]
    const float* ln2_g = (const float*)d_in[7];
    const float* ln2_b = (const float*)d_in[8];
    const float* w1    = (const float*)d_in[9];   // [L, DI, D]
    const float* b1    = (const float*)d_in[10];  // [L, DI]
    const float* w2    = (const float*)d_in[11];  // [L, D, DI]
    const float* b2    = (const float*)d_in[12];  // [L, D]
    const float* lnf_g = (const float*)d_in[13];
    const float* lnf_b = (const float*)d_in[14];
    const float* wprj  = (const float*)d_in[15];  // [1, D]
    float* out = (float*)d_out;

    char* ws = (char*)d_ws;
    float* xcur = (float*)ws;                       ws += (size_t)NROW * D_  * 4;  // fp32 residual stream
    __hip_bfloat16* lnb = (__hip_bfloat16*)ws;      ws += (size_t)NROW * D_  * 2;  // LN output (bf16 A-operand)
    float* xg2  = (float*)ws;                       ws += (size_t)NROW * G4H * 4;  // gate proj [s][g][hw][b]
    __hip_bfloat16* hb  = (__hip_bfloat16*)ws;      ws += (size_t)NROW * H_  * 2;  // LSTM h (bf16 A-operand)
    __hip_bfloat16* f1  = (__hip_bfloat16*)ws;      ws += (size_t)NROW * DI_ * 2;  // FFN hidden (bf16 A-operand)

    hipMemcpyAsync(xcur, src, (size_t)NROW * D_ * sizeof(float),
                   hipMemcpyDeviceToDevice, stream);

    for (int l = 0; l < L_; l++) {
        // --- janossy layer ---
        ln_kernel<<<NROW, 256, 0, stream>>>(xcur, ln1_g + (size_t)l * D_,
                                            ln1_b + (size_t)l * D_, lnb);
        mfma_gemm<0, 0, 0, 2><<<dim3(G4H / 64, NROW / 64), 256, 0, stream>>>(
            lnb, wih + (size_t)l * G4H * D_, nullptr, nullptr, xg2, NROW, G4H, D_);
        lstm_mfma2_kernel<<<dim3(40, 2), 256, 0, stream>>>(
            xg2, whh + (size_t)l * G4H * H_, hb);
        mfma_gemm<0, 0, 1, 0><<<dim3(D_ / 64, NROW / 64), 256, 0, stream>>>(
            hb, wfc + (size_t)l * D_ * H_, nullptr, xcur, xcur, NROW, D_, H_);
        // --- FFN ---
        ln_kernel<<<NROW, 256, 0, stream>>>(xcur, ln2_g + (size_t)l * D_,
                                            ln2_b + (size_t)l * D_, lnb);
        mfma_gemm<1, 1, 0, 1><<<dim3(DI_ / 64, NROW / 64), 256, 0, stream>>>(
            lnb, w1 + (size_t)l * DI_ * D_, b1 + (size_t)l * DI_, nullptr, f1, NROW, DI_, D_);
        mfma_gemm<1, 0, 1, 0><<<dim3(D_ / 64, NROW / 64), 256, 0, stream>>>(
            f1, w2 + (size_t)l * D_ * DI_, b2 + (size_t)l * D_, xcur, xcur, NROW, D_, DI_);
    }
    final_kernel<<<NROW, 256, 0, stream>>>(xcur, lnf_g, lnf_b, wprj, out);
}